// Round 6
// baseline (332.530 us; speedup 1.0000x reference)
//
#include <hip/hip_runtime.h>
#include <math.h>

// VectorExpansion: out[l, p, n] = sin(pi*x*n)/max(r,eps) * fc(r) * sqrt(2/rc) * x^l
// x = r/rc, rc=5, n=1..8, l=0..3.  fp32 in / fp32 out (verified R3).
//
// Structure (R5 post-mortem): dur_us = ~226us fixed harness overhead (1GB ws
// poison + out poison + input restores, visible in rocprof) + our kernels.
//  kernel 1: zero-fill d_out (268 MB @ ~6.3 TB/s ~= 43us).
//  kernel 2: sparse pair pass. R5 ran ~63us = TA-transaction-bound: random
//   structure per lane -> 9 cells loads + 6 position dword-gathers/thread each
//   touch ~60 cache lines per wave-instr (~900 L1 transactions/wave).
//  R6: (a) cells+offsets in LDS (padded to 12 floats/struct -> b128+b128+b32
//      per lane, random banks ~2-way = free); (b) positions as packed float3
//      dwordx3 loads: 6 scattered VMEM instrs -> 2.

#define RC_INV 0.2f
#define NORM 0.6324555320336759f  /* sqrt(2/5) */

struct f3u { float x, y, z; };   // 12 B packed, 4 B aligned -> global_load_dwordx3

__global__ __launch_bounds__(256) void zero_fill4(float4* __restrict__ out, int n4) {
    const int i = blockIdx.x * blockDim.x + threadIdx.x;
    if (i < n4) out[i] = make_float4(0.f, 0.f, 0.f, 0.f);
}

__global__ __launch_bounds__(256) void ve_sparse(
    const f3u* __restrict__ positions,          // [N] packed float3
    const float* __restrict__ cells,            // [S,3,3] fp32
    const int* __restrict__ cell_shifts,        // [P,3]
    const int* __restrict__ pairs,              // [P,2]
    const int* __restrict__ structure_pairs,    // [P]
    const int* __restrict__ structure_offsets,  // [S]
    float* __restrict__ out,                    // [4,P,8] fp32 (pre-zeroed)
    int P, int S)
{
    extern __shared__ float smem[];             // [12*S] padded cells, then [S] offsets
    float* sC  = smem;
    int*   sOf = (int*)(smem + 12 * S);
    for (int t = threadIdx.x; t < 9 * S; t += blockDim.x)
        sC[12 * (t / 9) + (t % 9)] = cells[t];
    for (int t = threadIdx.x; t < S; t += blockDim.x)
        sOf[t] = structure_offsets[t];
    __syncthreads();

    const int p = blockIdx.x * blockDim.x + threadIdx.x;
    if (p >= P) return;

    const int s   = structure_pairs[p];
    const int off = sOf[s];
    const int2 pr = ((const int2*)pairs)[p];

    const f3u pj = positions[off + pr.y];       // one dwordx3 gather
    const f3u pi = positions[off + pr.x];       // one dwordx3 gather

    const float shx = (float)cell_shifts[3*p + 0];
    const float shy = (float)cell_shifts[3*p + 1];
    const float shz = (float)cell_shifts[3*p + 2];

    const float* C = sC + 12*s;                 // row-major [c][d], LDS
    const float vx = pj.x - pi.x + shx*C[0] + shy*C[3] + shz*C[6];
    const float vy = pj.y - pi.y + shx*C[1] + shy*C[4] + shz*C[7];
    const float vz = pj.z - pi.z + shx*C[2] + shy*C[5] + shz*C[8];

    const float d2 = vx*vx + vy*vy + vz*vz + 1e-12f;
    const float r  = __builtin_amdgcn_sqrtf(d2);
    const float x  = r * RC_INV;

    if (x >= 1.0f) return;                      // fc==0 -> row already zeroed by fill

    // sin(pi*x), cos(pi*x) via HW trig (arg in revolutions; pi*x in [0,pi)
    // needs no range reduction): sin(pi*x) = v_sin(x/2)
    const float s1 = __builtin_amdgcn_sinf(0.5f * x);
    const float c1 = __builtin_amdgcn_cosf(0.5f * x);
    const float fc = 0.5f * (c1 + 1.0f);
    const float pref = fc * NORM * __builtin_amdgcn_rcpf(r);

    // sin(n*pi*x) by Chebyshev recurrence: s_{n+1} = 2*cos(pi*x)*s_n - s_{n-1}
    float b[8];
    {
        float sm1 = 0.0f, sn = s1;
        const float twoc = 2.0f * c1;
        #pragma unroll
        for (int n = 0; n < 8; ++n) {
            b[n] = pref * sn;
            const float nxt = twoc * sn - sm1;
            sm1 = sn; sn = nxt;
        }
    }

    // out flat (l,p,n) = l*P*8 + p*8 + n  ->  float4 slot (l*P+p)*2 + {0,1}
    float4* out4 = (float4*)out;
    float xl = 1.0f;
    #pragma unroll
    for (int l = 0; l < 4; ++l) {
        const long long base = 2LL * (1LL*l*P + p);
        out4[base + 0] = make_float4(b[0]*xl, b[1]*xl, b[2]*xl, b[3]*xl);
        out4[base + 1] = make_float4(b[4]*xl, b[5]*xl, b[6]*xl, b[7]*xl);
        xl *= x;
    }
}

extern "C" void kernel_launch(void* const* d_in, const int* in_sizes, int n_in,
                              void* d_out, int out_size, void* d_ws, size_t ws_size,
                              hipStream_t stream) {
    const f3u*   positions         = (const f3u*)d_in[0];
    const float* cells             = (const float*)d_in[1];
    const int*   cell_shifts       = (const int*)d_in[3];
    const int*   pairs             = (const int*)d_in[5];
    const int*   structure_pairs   = (const int*)d_in[7];
    const int*   structure_offsets = (const int*)d_in[8];
    float*       out               = (float*)d_out;

    const int P = in_sizes[7];          // structure_pairs is [P]
    const int S = in_sizes[8];          // structure_offsets is [S]
    const int block = 256;

    const int n4 = out_size / 4;        // out_size = 4*P*8, divisible by 4
    zero_fill4<<<(n4 + block - 1) / block, block, 0, stream>>>((float4*)out, n4);

    const size_t shmem = (size_t)(12 * S) * sizeof(float) + (size_t)S * sizeof(int);
    ve_sparse<<<(P + block - 1) / block, block, shmem, stream>>>(
        positions, cells, cell_shifts, pairs,
        structure_pairs, structure_offsets, out, P, S);
}